// Round 2
// baseline (308.909 us; speedup 1.0000x reference)
//
#include <hip/hip_runtime.h>
#include <hip/hip_bf16.h>
#include <cstdint>
#include <cstddef>

// MHA forward: B=2, T=2048, D=1024, H=16, dk=64. fp32 in/out, bf16 MFMA internal.
#define B_  2
#define T_  2048
#define D_  1024
#define H_  16
#define DK_ 64

typedef __hip_bfloat16 bf16;
typedef __bf16 bf16x8 __attribute__((ext_vector_type(8)));  // MFMA A/B frag (4 VGPRs)
typedef float  f32x4  __attribute__((ext_vector_type(4)));  // MFMA C/D frag

#define MFMA16(a, b, c) __builtin_amdgcn_mfma_f32_16x16x32_bf16((a), (b), (c), 0, 0, 0)

__device__ static inline void gld_lds16(const void* g, void* l) {
  // async global->LDS, 16B per lane; LDS dest is wave-uniform base + lane*16
  __builtin_amdgcn_global_load_lds((const __attribute__((address_space(1))) void*)g,
                                   (__attribute__((address_space(3))) void*)l, 16, 0, 0);
}

// ---------------- pack: x fp32 -> bf16 ----------------
__global__ __launch_bounds__(256) void pack_x_kernel(const float* __restrict__ x,
                                                     bf16* __restrict__ xb) {
  const int i = blockIdx.x * 256 + threadIdx.x;  // exactly 1M threads, 4 elems each
  const float4 v = reinterpret_cast<const float4*>(x)[i];
  union { ushort4 u; bf16 h[4]; } c;
  c.h[0] = __float2bfloat16(v.x);
  c.h[1] = __float2bfloat16(v.y);
  c.h[2] = __float2bfloat16(v.z);
  c.h[3] = __float2bfloat16(v.w);
  reinterpret_cast<ushort4*>(xb)[i] = c.u;
}

// ---------------- pack: W (D,D) fp32 row-major [k][n] -> bf16 transposed [n][k] ----------------
__global__ __launch_bounds__(256) void pack_w_kernel(const float* __restrict__ Wq,
                                                     const float* __restrict__ Wk,
                                                     const float* __restrict__ Wv,
                                                     const float* __restrict__ Wo,
                                                     bf16* __restrict__ Wt,    // [3072][1024]
                                                     bf16* __restrict__ Wot) { // [1024][1024]
  __shared__ bf16 t[64][65];  // +1 pad breaks bank conflicts on transposed read
  const int bid  = blockIdx.x;
  const int mat  = bid >> 8;       // 0..3 : Wq,Wk,Wv,Wo
  const int tile = bid & 255;      // 16x16 tiles of 64x64
  const int tr = tile >> 4, tc = tile & 15;
  const float* W = (mat == 0) ? Wq : (mat == 1) ? Wk : (mat == 2) ? Wv : Wo;
  const int tid = threadIdx.x;
#pragma unroll
  for (int i = 0; i < 16; ++i) {
    const int idx = i * 256 + tid;
    const int r = idx >> 6, c = idx & 63;
    t[r][c] = __float2bfloat16(W[(size_t)(tr * 64 + r) * D_ + tc * 64 + c]);
  }
  __syncthreads();
  bf16* dst = (mat == 3) ? Wot : (Wt + (size_t)mat * D_ * D_);
#pragma unroll
  for (int i = 0; i < 16; ++i) {
    const int idx = i * 256 + tid;
    const int n = idx >> 6, k = idx & 63;
    dst[(size_t)(tc * 64 + n) * D_ + tr * 64 + k] = t[k][n];
  }
}

// ---------------- 128x128 bf16 GEMM, BK=32, 4 waves (2x2 of 64x64) ----------------
// A: [M][K] row-major bf16.  Bt: [N][K] row-major bf16 (i.e. B transposed).
// MODE 0: QKV epilogue -> Qb/Kb [BH][T][64], Vt [BH][64][T], + bias (per 1024-col segment)
// MODE 1: out epilogue -> fp32 [M][1024] + bias0
template <int MODE>
__global__ __launch_bounds__(256, 2) void gemm128_kernel(
    const bf16* __restrict__ A, const bf16* __restrict__ Bt,
    const float* __restrict__ bias0, const float* __restrict__ bias1,
    const float* __restrict__ bias2,
    bf16* __restrict__ Qb, bf16* __restrict__ Kb, bf16* __restrict__ Vt,
    float* __restrict__ outp, int K) {
  __shared__ bf16 As[128 * 32];
  __shared__ bf16 Bs[128 * 32];
  const int tid  = threadIdx.x;
  const int lane = tid & 63, wid = tid >> 6;
  const int wr = wid >> 1, wc = wid & 1;
  const int l15 = lane & 15, lhi = lane >> 4;
  const int mbase = blockIdx.y * 128, nbase = blockIdx.x * 128;

  f32x4 acc[4][4] = {};

  const int r0  = tid >> 2;        // staged row for chunk p=0 (p=1 is +64)
  const int kc0 = (tid & 3) * 8;   // k offset within BK
  char* AsB = (char*)As;
  char* BsB = (char*)Bs;

  for (int kt = 0; kt < K; kt += 32) {
    gld_lds16(A  + (size_t)(mbase + r0)      * K + kt + kc0, AsB + wid * 1024);
    gld_lds16(A  + (size_t)(mbase + 64 + r0) * K + kt + kc0, AsB + 4096 + wid * 1024);
    gld_lds16(Bt + (size_t)(nbase + r0)      * K + kt + kc0, BsB + wid * 1024);
    gld_lds16(Bt + (size_t)(nbase + 64 + r0) * K + kt + kc0, BsB + 4096 + wid * 1024);
    __syncthreads();  // compiler drains vmcnt before barrier

    bf16x8 af[4], bfv[4];
#pragma unroll
    for (int m = 0; m < 4; ++m)
      af[m] = *reinterpret_cast<const bf16x8*>(&As[(wr * 64 + m * 16 + l15) * 32 + lhi * 8]);
#pragma unroll
    for (int n = 0; n < 4; ++n)
      bfv[n] = *reinterpret_cast<const bf16x8*>(&Bs[(wc * 64 + n * 16 + l15) * 32 + lhi * 8]);
#pragma unroll
    for (int m = 0; m < 4; ++m)
#pragma unroll
      for (int n = 0; n < 4; ++n)
        acc[m][n] = MFMA16(af[m], bfv[n], acc[m][n]);
    __syncthreads();
  }

  // epilogue: D layout col = lane&15, row = (lane>>4)*4 + j
#pragma unroll
  for (int n = 0; n < 4; ++n) {
    const int col = nbase + wc * 64 + n * 16 + l15;
    if (MODE == 0) {
      const int seg  = col >> 10;      // 0=Q 1=K 2=V (uniform per block: N tiles are 128-wide)
      const int ncol = col & 1023;
      const float* bias = (seg == 0) ? bias0 : (seg == 1) ? bias1 : bias2;
      const float bv_ = bias[ncol];
      const int h = ncol >> 6, dk = ncol & 63;
#pragma unroll
      for (int m = 0; m < 4; ++m) {
#pragma unroll
        for (int j = 0; j < 4; ++j) {
          const int row = mbase + wr * 64 + m * 16 + lhi * 4 + j;
          const int b = row >> 11, t = row & 2047;
          const int bh = b * H_ + h;
          const bf16 hv = __float2bfloat16(acc[m][n][j] + bv_);
          if (seg == 0)      Qb[((size_t)bh * T_ + t) * DK_ + dk] = hv;
          else if (seg == 1) Kb[((size_t)bh * T_ + t) * DK_ + dk] = hv;
          else               Vt[((size_t)bh * DK_ + dk) * T_ + t] = hv;  // transposed V
        }
      }
    } else {
      const float bv_ = bias0[col];
#pragma unroll
      for (int m = 0; m < 4; ++m)
#pragma unroll
        for (int j = 0; j < 4; ++j) {
          const int row = mbase + wr * 64 + m * 16 + lhi * 4 + j;
          outp[(size_t)row * D_ + col] = acc[m][n][j] + bv_;
        }
    }
  }
}

// ---------------- flash attention (causal), 4 independent waves/block, 16 q-rows/wave ----------------
// KV tile = 64 per iteration, register-prefetched K (next tile) and V (current tile).
// Q,K: [BH][T][64] bf16.  Vt: [BH][64][T] bf16.  Mg: [B*T][D] bf16 (merged heads).
#define PSTR 88  // P transpose buffer row stride in bf16 (176B): conflict-free b128 reads
__global__ __launch_bounds__(256, 3) void attn_kernel(const bf16* __restrict__ Q,
                                                      const bf16* __restrict__ Kg,
                                                      const bf16* __restrict__ Vt,
                                                      bf16* __restrict__ Mg) {
  __shared__ bf16 plds[4][16 * PSTR];  // per-wave P transpose buffer
  const int tid = threadIdx.x, lane = tid & 63, wid = tid >> 6;
  const int l15 = lane & 15, lhi = lane >> 4;
  const int bh = blockIdx.x >> 5;   // 32 q-tiles of 64 per (b,h)
  const int qt = blockIdx.x & 31;
  const int qbase = qt * 64 + wid * 16;
  const int b = bh >> 4, h = bh & 15;

  const bf16* Qp = Q  + (size_t)bh * T_ * DK_;
  const bf16* Kp = Kg + (size_t)bh * T_ * DK_;
  const bf16* Vp = Vt + (size_t)bh * DK_ * T_;

  const int qrow = qbase + l15;
  const bf16x8 qf0 = *reinterpret_cast<const bf16x8*>(&Qp[(size_t)qrow * DK_ + lhi * 8]);
  const bf16x8 qf1 = *reinterpret_cast<const bf16x8*>(&Qp[(size_t)qrow * DK_ + 32 + lhi * 8]);

  f32x4 o[4] = {};
  float mrow[4] = {-1e30f, -1e30f, -1e30f, -1e30f};
  float lrow[4] = {0.f, 0.f, 0.f, 0.f};

  bf16* pw = plds[wid];
  const int nt = qt + 1;  // number of 64-wide kv tiles (uniform across the block's waves)

  // preload K tile 0: kf[s*2+h] = K[kv0 + s*16 + l15][h*32 + lhi*8 ..+7]
  bf16x8 kf[8];
#pragma unroll
  for (int s = 0; s < 4; ++s)
#pragma unroll
    for (int hh = 0; hh < 2; ++hh)
      kf[s * 2 + hh] = *reinterpret_cast<const bf16x8*>(
          &Kp[(size_t)(s * 16 + l15) * DK_ + hh * 32 + lhi * 8]);

  for (int t = 0; t < nt; ++t) {
    const int kv0 = t * 64;

    // S = Q K^T for 16 q-rows x 64 kv-cols (four 16x16 tiles, contraction dk=64)
    f32x4 sv[4];
#pragma unroll
    for (int s = 0; s < 4; ++s) {
      f32x4 z = {};
      z = MFMA16(qf0, kf[s * 2 + 0], z);
      sv[s] = MFMA16(qf1, kf[s * 2 + 1], z);
    }

    // prefetch K for next tile (clamped; hidden under softmax + PV)
    const int kvn = (t + 1 < nt ? t + 1 : t) * 64;
#pragma unroll
    for (int s = 0; s < 4; ++s)
#pragma unroll
      for (int hh = 0; hh < 2; ++hh)
        kf[s * 2 + hh] = *reinterpret_cast<const bf16x8*>(
            &Kp[(size_t)(kvn + s * 16 + l15) * DK_ + hh * 32 + lhi * 8]);

    // V fragments for this tile (latency hidden under softmax)
    // vf[d*2+s2] = V[kv0 + s2*32 + lhi*8 ..+7][d*16 + l15] from transposed V
    bf16x8 vf[8];
#pragma unroll
    for (int d = 0; d < 4; ++d)
#pragma unroll
      for (int s2 = 0; s2 < 2; ++s2)
        vf[d * 2 + s2] = *reinterpret_cast<const bf16x8*>(
            &Vp[(size_t)(d * 16 + l15) * T_ + kv0 + s2 * 32 + lhi * 8]);

    // scale + causal mask. S layout: col = kv0 + s*16 + l15, row = qbase + lhi*4 + j
    float mx[4];
#pragma unroll
    for (int j = 0; j < 4; ++j) mx[j] = -1e30f;
#pragma unroll
    for (int s = 0; s < 4; ++s) {
      const int c = kv0 + s * 16 + l15;
#pragma unroll
      for (int j = 0; j < 4; ++j) {
        const int r = qbase + lhi * 4 + j;
        const float v = (c <= r) ? sv[s][j] * 0.125f : -1e30f;
        sv[s][j] = v;
        mx[j] = fmaxf(mx[j], v);
      }
    }
    // row max across the 16 lanes holding this row's columns
#pragma unroll
    for (int off = 8; off >= 1; off >>= 1)
#pragma unroll
      for (int j = 0; j < 4; ++j)
        mx[j] = fmaxf(mx[j], __shfl_xor(mx[j], off, 64));

    float sc[4], rs[4];
#pragma unroll
    for (int j = 0; j < 4; ++j) {
      const float mn = fmaxf(mrow[j], mx[j]);
      sc[j] = __expf(mrow[j] - mn);
      mrow[j] = mn;
      rs[j] = 0.f;
#pragma unroll
      for (int s = 0; s < 4; ++s) {
        const float p = __expf(sv[s][j] - mn);
        sv[s][j] = p;
        rs[j] += p;
      }
    }
#pragma unroll
    for (int off = 8; off >= 1; off >>= 1)
#pragma unroll
      for (int j = 0; j < 4; ++j)
        rs[j] += __shfl_xor(rs[j], off, 64);

#pragma unroll
    for (int j = 0; j < 4; ++j) {
      lrow[j] = lrow[j] * sc[j] + rs[j];
      o[0][j] *= sc[j]; o[1][j] *= sc[j]; o[2][j] *= sc[j]; o[3][j] *= sc[j];
    }

    // transpose P via per-wave LDS: buffer[q = lhi*4+j][kv = s*16 + l15]
#pragma unroll
    for (int s = 0; s < 4; ++s)
#pragma unroll
      for (int j = 0; j < 4; ++j)
        pw[(lhi * 4 + j) * PSTR + s * 16 + l15] = __float2bfloat16(sv[s][j]);
    asm volatile("s_waitcnt lgkmcnt(0)" ::: "memory");  // wave-internal write->read fence
    const bf16x8 pf0 = *reinterpret_cast<const bf16x8*>(&pw[l15 * PSTR + lhi * 8]);
    const bf16x8 pf1 = *reinterpret_cast<const bf16x8*>(&pw[l15 * PSTR + 32 + lhi * 8]);

    // O += P V
#pragma unroll
    for (int d = 0; d < 4; ++d) {
      o[d] = MFMA16(pf0, vf[d * 2 + 0], o[d]);
      o[d] = MFMA16(pf1, vf[d * 2 + 1], o[d]);
    }
  }

#pragma unroll
  for (int j = 0; j < 4; ++j) {
    const float inv = 1.0f / lrow[j];
    const int t = qbase + lhi * 4 + j;
#pragma unroll
    for (int d = 0; d < 4; ++d)
      Mg[((size_t)b * T_ + t) * D_ + h * DK_ + d * 16 + l15] = __float2bfloat16(o[d][j] * inv);
  }
}

// ---------------- launch ----------------
extern "C" void kernel_launch(void* const* d_in, const int* in_sizes, int n_in,
                              void* d_out, int out_size, void* d_ws, size_t ws_size,
                              hipStream_t stream) {
  (void)in_sizes; (void)n_in; (void)out_size; (void)ws_size;
  const float* x  = (const float*)d_in[0];
  const float* Wq = (const float*)d_in[1];
  const float* bq = (const float*)d_in[2];
  const float* Wk = (const float*)d_in[3];
  const float* bk = (const float*)d_in[4];
  const float* Wv = (const float*)d_in[5];
  const float* bv = (const float*)d_in[6];
  const float* Wo = (const float*)d_in[7];
  const float* bo = (const float*)d_in[8];
  float* out = (float*)d_out;

  // workspace layout (40 MB): Mg aliases xb (xb dead after QKV GEMM, attn runs after)
  char* ws = (char*)d_ws;
  bf16* xb  = (bf16*)(ws);                       // 8 MB [4096][1024]
  bf16* Mg  = (bf16*)(ws);                       // 8 MB [4096][1024] (alias, written by attn)
  bf16* Wt  = (bf16*)(ws + (size_t)( 8u << 20)); // 6 MB [3072][1024] (Wq|Wk|Wv transposed)
  bf16* Wot = (bf16*)(ws + (size_t)(14u << 20)); // 2 MB [1024][1024] (Wo transposed)
  bf16* Qb  = (bf16*)(ws + (size_t)(16u << 20)); // 8 MB [32][2048][64]
  bf16* Kb  = (bf16*)(ws + (size_t)(24u << 20)); // 8 MB [32][2048][64]
  bf16* Vt  = (bf16*)(ws + (size_t)(32u << 20)); // 8 MB [32][64][2048]

  pack_x_kernel<<<4096, 256, 0, stream>>>(x, xb);
  pack_w_kernel<<<1024, 256, 0, stream>>>(Wq, Wk, Wv, Wo, Wt, Wot);
  // fused QKV: C[4096][3072] = xb @ [Wq|Wk|Wv]
  gemm128_kernel<0><<<dim3(24, 32), 256, 0, stream>>>(xb, Wt, bq, bk, bv, Qb, Kb, Vt, nullptr, 1024);
  attn_kernel<<<dim3(1024), 256, 0, stream>>>(Qb, Kb, Vt, Mg);
  // out[4096][1024] = Mg @ Wo + bo
  gemm128_kernel<1><<<dim3(8, 32), 256, 0, stream>>>(Mg, Wot, bo, nullptr, nullptr, nullptr, nullptr, nullptr, out, 1024);
}

// Round 3
// 167.509 us; speedup vs baseline: 1.8441x; 1.8441x over previous
//
#include <hip/hip_runtime.h>
#include <hip/hip_bf16.h>
#include <cstdint>
#include <cstddef>

// MHA forward: B=2, T=2048, D=1024, H=16, dk=64. fp32 in/out, bf16 MFMA internal.
#define B_  2
#define T_  2048
#define D_  1024
#define H_  16
#define DK_ 64

typedef __hip_bfloat16 bf16;
typedef __bf16 bf16x8 __attribute__((ext_vector_type(8)));  // MFMA A/B frag (4 VGPRs)
typedef float  f32x4  __attribute__((ext_vector_type(4)));  // MFMA C/D frag

#define MFMA16(a, b, c) __builtin_amdgcn_mfma_f32_16x16x32_bf16((a), (b), (c), 0, 0, 0)

__device__ static inline void gld_lds16(const void* g, void* l) {
  // async global->LDS, 16B per lane; LDS dest is wave-uniform base + lane*16
  __builtin_amdgcn_global_load_lds((const __attribute__((address_space(1))) void*)g,
                                   (__attribute__((address_space(3))) void*)l, 16, 0, 0);
}

// ---------------- pack: x fp32 -> bf16 ----------------
__global__ __launch_bounds__(256) void pack_x_kernel(const float* __restrict__ x,
                                                     bf16* __restrict__ xb) {
  const int i = blockIdx.x * 256 + threadIdx.x;  // exactly 1M threads, 4 elems each
  const float4 v = reinterpret_cast<const float4*>(x)[i];
  union { ushort4 u; bf16 h[4]; } c;
  c.h[0] = __float2bfloat16(v.x);
  c.h[1] = __float2bfloat16(v.y);
  c.h[2] = __float2bfloat16(v.z);
  c.h[3] = __float2bfloat16(v.w);
  reinterpret_cast<ushort4*>(xb)[i] = c.u;
}

// ---------------- pack: W (D,D) fp32 row-major [k][n] -> bf16 transposed [n][k] ----------------
__global__ __launch_bounds__(256) void pack_w_kernel(const float* __restrict__ Wq,
                                                     const float* __restrict__ Wk,
                                                     const float* __restrict__ Wv,
                                                     const float* __restrict__ Wo,
                                                     bf16* __restrict__ Wt,    // [3072][1024]
                                                     bf16* __restrict__ Wot) { // [1024][1024]
  __shared__ bf16 t[64][65];  // +1 pad breaks bank conflicts on transposed read
  const int bid  = blockIdx.x;
  const int mat  = bid >> 8;       // 0..3 : Wq,Wk,Wv,Wo
  const int tile = bid & 255;      // 16x16 tiles of 64x64
  const int tr = tile >> 4, tc = tile & 15;
  const float* W = (mat == 0) ? Wq : (mat == 1) ? Wk : (mat == 2) ? Wv : Wo;
  const int tid = threadIdx.x;
#pragma unroll
  for (int i = 0; i < 16; ++i) {
    const int idx = i * 256 + tid;
    const int r = idx >> 6, c = idx & 63;
    t[r][c] = __float2bfloat16(W[(size_t)(tr * 64 + r) * D_ + tc * 64 + c]);
  }
  __syncthreads();
  bf16* dst = (mat == 3) ? Wot : (Wt + (size_t)mat * D_ * D_);
#pragma unroll
  for (int i = 0; i < 16; ++i) {
    const int idx = i * 256 + tid;
    const int n = idx >> 6, k = idx & 63;
    dst[(size_t)(tc * 64 + n) * D_ + tr * 64 + k] = t[k][n];
  }
}

// ---------------- 128x128 bf16 GEMM, BK=32, 4 waves (2x2 of 64x64) ----------------
// A: [M][K] row-major bf16.  Bt: [N][K] row-major bf16 (i.e. B transposed).
// MODE 0: QKV epilogue -> Qb/Kb [BH][T][64], Vt [BH][64][T], + bias; Q scaled by 1/8.
// MODE 1: out epilogue -> fp32 [M][1024] + bias0
template <int MODE>
__global__ __launch_bounds__(256, 2) void gemm128_kernel(
    const bf16* __restrict__ A, const bf16* __restrict__ Bt,
    const float* __restrict__ bias0, const float* __restrict__ bias1,
    const float* __restrict__ bias2,
    bf16* __restrict__ Qb, bf16* __restrict__ Kb, bf16* __restrict__ Vt,
    float* __restrict__ outp, int K) {
  __shared__ bf16 As[128 * 32];
  __shared__ bf16 Bs[128 * 32];
  const int tid  = threadIdx.x;
  const int lane = tid & 63, wid = tid >> 6;
  const int wr = wid >> 1, wc = wid & 1;
  const int l15 = lane & 15, lhi = lane >> 4;
  const int mbase = blockIdx.y * 128, nbase = blockIdx.x * 128;

  f32x4 acc[4][4] = {};

  const int r0  = tid >> 2;        // staged row for chunk p=0 (p=1 is +64)
  const int kc0 = (tid & 3) * 8;   // k offset within BK
  char* AsB = (char*)As;
  char* BsB = (char*)Bs;

  for (int kt = 0; kt < K; kt += 32) {
    gld_lds16(A  + (size_t)(mbase + r0)      * K + kt + kc0, AsB + wid * 1024);
    gld_lds16(A  + (size_t)(mbase + 64 + r0) * K + kt + kc0, AsB + 4096 + wid * 1024);
    gld_lds16(Bt + (size_t)(nbase + r0)      * K + kt + kc0, BsB + wid * 1024);
    gld_lds16(Bt + (size_t)(nbase + 64 + r0) * K + kt + kc0, BsB + 4096 + wid * 1024);
    __syncthreads();  // compiler drains vmcnt before barrier

    bf16x8 af[4], bfv[4];
#pragma unroll
    for (int m = 0; m < 4; ++m)
      af[m] = *reinterpret_cast<const bf16x8*>(&As[(wr * 64 + m * 16 + l15) * 32 + lhi * 8]);
#pragma unroll
    for (int n = 0; n < 4; ++n)
      bfv[n] = *reinterpret_cast<const bf16x8*>(&Bs[(wc * 64 + n * 16 + l15) * 32 + lhi * 8]);
#pragma unroll
    for (int m = 0; m < 4; ++m)
#pragma unroll
      for (int n = 0; n < 4; ++n)
        acc[m][n] = MFMA16(af[m], bfv[n], acc[m][n]);
    __syncthreads();
  }

  // epilogue: D layout col = lane&15, row = (lane>>4)*4 + j
#pragma unroll
  for (int n = 0; n < 4; ++n) {
    const int col = nbase + wc * 64 + n * 16 + l15;
    if (MODE == 0) {
      const int seg  = col >> 10;      // 0=Q 1=K 2=V (uniform per block: N tiles are 128-wide)
      const int ncol = col & 1023;
      const float* bias = (seg == 0) ? bias0 : (seg == 1) ? bias1 : bias2;
      const float bv_ = bias[ncol];
      const int h = ncol >> 6, dk = ncol & 63;
#pragma unroll
      for (int m = 0; m < 4; ++m) {
#pragma unroll
        for (int j = 0; j < 4; ++j) {
          const int row = mbase + wr * 64 + m * 16 + lhi * 4 + j;
          const int b = row >> 11, t = row & 2047;
          const int bh = b * H_ + h;
          float outv = acc[m][n][j] + bv_;
          if (seg == 0) outv *= 0.125f;  // fold 1/sqrt(dk) into Q
          const bf16 hv = __float2bfloat16(outv);
          if (seg == 0)      Qb[((size_t)bh * T_ + t) * DK_ + dk] = hv;
          else if (seg == 1) Kb[((size_t)bh * T_ + t) * DK_ + dk] = hv;
          else               Vt[((size_t)bh * DK_ + dk) * T_ + t] = hv;  // transposed V
        }
      }
    } else {
      const float bv_ = bias0[col];
#pragma unroll
      for (int m = 0; m < 4; ++m)
#pragma unroll
        for (int j = 0; j < 4; ++j) {
          const int row = mbase + wr * 64 + m * 16 + lhi * 4 + j;
          outp[(size_t)row * D_ + col] = acc[m][n][j] + bv_;
        }
    }
  }
}

// ---------------- flash attention (causal): LDS-staged K/V, double-buffered ----------------
// Block = 4 waves x 16 q-rows = 64 q rows (one q-tile). KV tile = 64, shared via LDS.
// Q: [BH][T][64] bf16 (pre-scaled by 1/8).  K: [BH][T][64].  Vt: [BH][64][T].
// LDS K/V tiles stored as [64][8 chunks of 16B] with chunk c at slot c^(r&7) (T2 swizzle,
// applied on the global SOURCE address per rule 21; reads apply the same XOR).
#define PSTR 72  // P transpose buffer row stride in bf16 (144B)
__global__ __launch_bounds__(256, 3) void attn_kernel(const bf16* __restrict__ Q,
                                                      const bf16* __restrict__ Kg,
                                                      const bf16* __restrict__ Vt,
                                                      bf16* __restrict__ Mg) {
  __shared__ __align__(16) bf16 Kl[2][64 * 64];
  __shared__ __align__(16) bf16 Vl[2][64 * 64];
  __shared__ __align__(16) bf16 plds[4][16 * PSTR];
  const int tid = threadIdx.x, lane = tid & 63, wid = tid >> 6;
  const int l15 = lane & 15, lhi = lane >> 4;
  const int qt = blockIdx.x >> 5;   // 0..31  (qt-major: CUs get a mix of lengths)
  const int bh = blockIdx.x & 31;
  const int qbase = qt * 64 + wid * 16;
  const int b = bh >> 4, h = bh & 15;

  const bf16* Qp = Q  + (size_t)bh * T_ * DK_;
  const bf16* Kp = Kg + (size_t)bh * T_ * DK_;
  const bf16* Vp = Vt + (size_t)bh * DK_ * T_;

  const bf16x8 qf0 = *reinterpret_cast<const bf16x8*>(&Qp[(size_t)(qbase + l15) * DK_ + lhi * 8]);
  const bf16x8 qf1 = *reinterpret_cast<const bf16x8*>(&Qp[(size_t)(qbase + l15) * DK_ + 32 + lhi * 8]);

  f32x4 o[4] = {};
  float mrow[4] = {-1e30f, -1e30f, -1e30f, -1e30f};
  float lrow[4] = {0.f, 0.f, 0.f, 0.f};
  bf16* pw = plds[wid];

  const int nt = qt + 1;  // kv tiles (64 wide)

  // ---- staging helper (inlined twice): stage tile `tile` into buffer bi ----
  // dest linear chunk idx = it*256 + tid; row r = idx>>3, dest chunk c = idx&7,
  // source chunk cs = c ^ (r&7). Wave-uniform LDS base + lane*16 (HW rule).
#define STAGE_KV(bi, tile)                                                              \
  {                                                                                     \
    const int kvs = (tile) * 64;                                                        \
    _Pragma("unroll")                                                                   \
    for (int it = 0; it < 2; ++it) {                                                    \
      const int idx = it * 256 + tid;                                                   \
      const int r = idx >> 3, c = idx & 7;                                              \
      const int cs = c ^ (r & 7);                                                       \
      const int ubase = (it * 256 + wid * 64) * 16;                                     \
      gld_lds16(Kp + (size_t)(kvs + r) * DK_ + cs * 8, (char*)Kl[bi] + ubase);          \
      gld_lds16(Vp + (size_t)r * T_ + kvs + cs * 8,    (char*)Vl[bi] + ubase);          \
    }                                                                                   \
  }

  STAGE_KV(0, 0);
  __syncthreads();

  for (int t = 0; t < nt; ++t) {
    const int kv0 = t * 64;
    const int cur = t & 1;
    if (t + 1 < nt) STAGE_KV((t + 1) & 1, t + 1);  // overlap staging with compute

    const char* Kb_ = (const char*)Kl[cur];
    const char* Vb_ = (const char*)Vl[cur];
    const int rsw = (l15 & 7);  // row-derived XOR for swizzled chunk reads

    // ---- S = Q K^T : 4 s-tiles of 16 cols; skip tiles fully above the causal line
    f32x4 sv[4];
#pragma unroll
    for (int s = 0; s < 4; ++s) {
      const int cbase = kv0 + s * 16;
      if (cbase <= qbase + 15) {  // wave-uniform liveness
        const int row = s * 16 + l15;
        const bf16x8 k0 = *reinterpret_cast<const bf16x8*>(Kb_ + row * 128 + ((lhi       ^ rsw) * 16));
        const bf16x8 k1 = *reinterpret_cast<const bf16x8*>(Kb_ + row * 128 + (((4 + lhi) ^ rsw) * 16));
        f32x4 z = {};
        z = MFMA16(qf0, k0, z);
        sv[s] = MFMA16(qf1, k1, z);
      } else {
#pragma unroll
        for (int j = 0; j < 4; ++j) sv[s][j] = -1e30f;
      }
    }

    // ---- V fragments from LDS (latency hidden under softmax)
    bf16x8 vf[8];
#pragma unroll
    for (int d = 0; d < 4; ++d) {
      const int row = d * 16 + l15;
#pragma unroll
      for (int s2 = 0; s2 < 2; ++s2)
        vf[d * 2 + s2] = *reinterpret_cast<const bf16x8*>(
            Vb_ + row * 128 + (((s2 * 4 + lhi) ^ rsw) * 16));
    }

    // ---- causal mask: only the diagonal-straddling s-tile needs per-element cndmask
#pragma unroll
    for (int s = 0; s < 4; ++s) {
      const int cbase = kv0 + s * 16;
      if (cbase <= qbase + 15 && cbase + 15 > qbase) {
        const int c = cbase + l15;
#pragma unroll
        for (int j = 0; j < 4; ++j) {
          const int r = qbase + lhi * 4 + j;
          sv[s][j] = (c <= r) ? sv[s][j] : -1e30f;
        }
      }
    }

    // ---- online softmax over 64 cols (16 lanes x 4 s-tiles)
    float mx[4];
#pragma unroll
    for (int j = 0; j < 4; ++j)
      mx[j] = fmaxf(fmaxf(sv[0][j], sv[1][j]), fmaxf(sv[2][j], sv[3][j]));
#pragma unroll
    for (int off = 8; off >= 1; off >>= 1)
#pragma unroll
      for (int j = 0; j < 4; ++j)
        mx[j] = fmaxf(mx[j], __shfl_xor(mx[j], off, 64));

    float sc[4], rs[4];
#pragma unroll
    for (int j = 0; j < 4; ++j) {
      const float mn = fmaxf(mrow[j], mx[j]);
      sc[j] = __expf(mrow[j] - mn);
      mrow[j] = mn;
      rs[j] = 0.f;
#pragma unroll
      for (int s = 0; s < 4; ++s) {
        const float p = __expf(sv[s][j] - mn);
        sv[s][j] = p;
        rs[j] += p;
      }
    }
#pragma unroll
    for (int off = 8; off >= 1; off >>= 1)
#pragma unroll
      for (int j = 0; j < 4; ++j)
        rs[j] += __shfl_xor(rs[j], off, 64);

#pragma unroll
    for (int j = 0; j < 4; ++j) {
      lrow[j] = lrow[j] * sc[j] + rs[j];
      o[0][j] *= sc[j]; o[1][j] *= sc[j]; o[2][j] *= sc[j]; o[3][j] *= sc[j];
    }

    // ---- transpose P via per-wave LDS: buffer[q = lhi*4+j][kv = s*16+l15]
#pragma unroll
    for (int s = 0; s < 4; ++s)
#pragma unroll
      for (int j = 0; j < 4; ++j)
        pw[(lhi * 4 + j) * PSTR + s * 16 + l15] = __float2bfloat16(sv[s][j]);
    asm volatile("s_waitcnt lgkmcnt(0)" ::: "memory");  // wave-internal write->read fence
    const bf16x8 pf0 = *reinterpret_cast<const bf16x8*>(&pw[l15 * PSTR + lhi * 8]);
    const bf16x8 pf1 = *reinterpret_cast<const bf16x8*>(&pw[l15 * PSTR + 32 + lhi * 8]);

    // ---- O += P V
#pragma unroll
    for (int d = 0; d < 4; ++d) {
      o[d] = MFMA16(pf0, vf[d * 2 + 0], o[d]);
      o[d] = MFMA16(pf1, vf[d * 2 + 1], o[d]);
    }

    __syncthreads();  // drains vmcnt (next tile staged) + orders buffer reuse
  }

#pragma unroll
  for (int j = 0; j < 4; ++j) {
    const float inv = 1.0f / lrow[j];
    const int t = qbase + lhi * 4 + j;
#pragma unroll
    for (int d = 0; d < 4; ++d)
      Mg[((size_t)b * T_ + t) * D_ + h * DK_ + d * 16 + l15] = __float2bfloat16(o[d][j] * inv);
  }
}

// ---------------- launch ----------------
extern "C" void kernel_launch(void* const* d_in, const int* in_sizes, int n_in,
                              void* d_out, int out_size, void* d_ws, size_t ws_size,
                              hipStream_t stream) {
  (void)in_sizes; (void)n_in; (void)out_size; (void)ws_size;
  const float* x  = (const float*)d_in[0];
  const float* Wq = (const float*)d_in[1];
  const float* bq = (const float*)d_in[2];
  const float* Wk = (const float*)d_in[3];
  const float* bk = (const float*)d_in[4];
  const float* Wv = (const float*)d_in[5];
  const float* bv = (const float*)d_in[6];
  const float* Wo = (const float*)d_in[7];
  const float* bo = (const float*)d_in[8];
  float* out = (float*)d_out;

  // workspace layout (40 MB): Mg aliases xb (xb dead after QKV GEMM, attn runs after)
  char* ws = (char*)d_ws;
  bf16* xb  = (bf16*)(ws);                       // 8 MB [4096][1024]
  bf16* Mg  = (bf16*)(ws);                       // 8 MB [4096][1024] (alias, written by attn)
  bf16* Wt  = (bf16*)(ws + (size_t)( 8u << 20)); // 6 MB [3072][1024] (Wq|Wk|Wv transposed)
  bf16* Wot = (bf16*)(ws + (size_t)(14u << 20)); // 2 MB [1024][1024] (Wo transposed)
  bf16* Qb  = (bf16*)(ws + (size_t)(16u << 20)); // 8 MB [32][2048][64]
  bf16* Kb  = (bf16*)(ws + (size_t)(24u << 20)); // 8 MB [32][2048][64]
  bf16* Vt  = (bf16*)(ws + (size_t)(32u << 20)); // 8 MB [32][64][2048]

  pack_x_kernel<<<4096, 256, 0, stream>>>(x, xb);
  pack_w_kernel<<<1024, 256, 0, stream>>>(Wq, Wk, Wv, Wo, Wt, Wot);
  // fused QKV: C[4096][3072] = xb @ [Wq|Wk|Wv]
  gemm128_kernel<0><<<dim3(24, 32), 256, 0, stream>>>(xb, Wt, bq, bk, bv, Qb, Kb, Vt, nullptr, 1024);
  attn_kernel<<<dim3(1024), 256, 0, stream>>>(Qb, Kb, Vt, Mg);
  // out[4096][1024] = Mg @ Wo + bo
  gemm128_kernel<1><<<dim3(8, 32), 256, 0, stream>>>(Mg, Wot, bo, nullptr, nullptr, nullptr, nullptr, nullptr, out, 1024);
}

// Round 4
// 155.642 us; speedup vs baseline: 1.9847x; 1.0762x over previous
//
#include <hip/hip_runtime.h>
#include <hip/hip_bf16.h>
#include <cstdint>
#include <cstddef>

// MHA forward: B=2, T=2048, D=1024, H=16, dk=64. fp32 in/out, bf16 MFMA internal.
#define B_  2
#define T_  2048
#define D_  1024
#define H_  16
#define DK_ 64

typedef __hip_bfloat16 bf16;
typedef __bf16 bf16x8 __attribute__((ext_vector_type(8)));  // MFMA A/B frag (4 VGPRs)
typedef float  f32x4  __attribute__((ext_vector_type(4)));  // MFMA C/D frag

#define MFMA16(a, b, c) __builtin_amdgcn_mfma_f32_16x16x32_bf16((a), (b), (c), 0, 0, 0)

// Q production scale: 1/sqrt(64) * log2(e)  (softmax done in exp2 domain)
#define SCALE_Q 0.1803368801111137f

__device__ static inline void gld_lds16(const void* g, void* l) {
  // async global->LDS, 16B per lane; LDS dest is wave-uniform base + lane*16
  __builtin_amdgcn_global_load_lds((const __attribute__((address_space(1))) void*)g,
                                   (__attribute__((address_space(3))) void*)l, 16, 0, 0);
}

// ---------------- pack: x fp32 -> bf16 ----------------
__global__ __launch_bounds__(256) void pack_x_kernel(const float* __restrict__ x,
                                                     bf16* __restrict__ xb) {
  const int i = blockIdx.x * 256 + threadIdx.x;  // exactly 1M threads, 4 elems each
  const float4 v = reinterpret_cast<const float4*>(x)[i];
  union { ushort4 u; bf16 h[4]; } c;
  c.h[0] = __float2bfloat16(v.x);
  c.h[1] = __float2bfloat16(v.y);
  c.h[2] = __float2bfloat16(v.z);
  c.h[3] = __float2bfloat16(v.w);
  reinterpret_cast<ushort4*>(xb)[i] = c.u;
}

// ---------------- pack: W (D,D) fp32 row-major [k][n] -> bf16 transposed [n][k] ----------------
__global__ __launch_bounds__(256) void pack_w_kernel(const float* __restrict__ Wq,
                                                     const float* __restrict__ Wk,
                                                     const float* __restrict__ Wv,
                                                     const float* __restrict__ Wo,
                                                     bf16* __restrict__ Wt,    // [3072][1024]
                                                     bf16* __restrict__ Wot) { // [1024][1024]
  __shared__ bf16 t[64][65];  // +1 pad breaks bank conflicts on transposed read
  const int bid  = blockIdx.x;
  const int mat  = bid >> 8;       // 0..3 : Wq,Wk,Wv,Wo
  const int tile = bid & 255;      // 16x16 tiles of 64x64
  const int tr = tile >> 4, tc = tile & 15;
  const float* W = (mat == 0) ? Wq : (mat == 1) ? Wk : (mat == 2) ? Wv : Wo;
  const int tid = threadIdx.x;
#pragma unroll
  for (int i = 0; i < 16; ++i) {
    const int idx = i * 256 + tid;
    const int r = idx >> 6, c = idx & 63;
    t[r][c] = __float2bfloat16(W[(size_t)(tr * 64 + r) * D_ + tc * 64 + c]);
  }
  __syncthreads();
  bf16* dst = (mat == 3) ? Wot : (Wt + (size_t)mat * D_ * D_);
#pragma unroll
  for (int i = 0; i < 16; ++i) {
    const int idx = i * 256 + tid;
    const int n = idx >> 6, k = idx & 63;
    dst[(size_t)(tc * 64 + n) * D_ + tr * 64 + k] = t[k][n];
  }
}

// ---------------- 128x128 bf16 GEMM, BK=32, 4 waves (2x2 of 64x64) ----------------
// A: [M][K] row-major bf16.  Bt: [N][K] row-major bf16 (i.e. B transposed).
// MODE 0: QKV epilogue -> Qb/Kb [BH][T][64], Vt [BH][64][T], + bias; Q scaled by SCALE_Q.
// MODE 1: out epilogue -> fp32 [M][1024] + bias0
template <int MODE>
__global__ __launch_bounds__(256, 2) void gemm128_kernel(
    const bf16* __restrict__ A, const bf16* __restrict__ Bt,
    const float* __restrict__ bias0, const float* __restrict__ bias1,
    const float* __restrict__ bias2,
    bf16* __restrict__ Qb, bf16* __restrict__ Kb, bf16* __restrict__ Vt,
    float* __restrict__ outp, int K) {
  __shared__ bf16 As[128 * 32];
  __shared__ bf16 Bs[128 * 32];
  const int tid  = threadIdx.x;
  const int lane = tid & 63, wid = tid >> 6;
  const int wr = wid >> 1, wc = wid & 1;
  const int l15 = lane & 15, lhi = lane >> 4;
  const int mbase = blockIdx.y * 128, nbase = blockIdx.x * 128;

  f32x4 acc[4][4] = {};

  const int r0  = tid >> 2;        // staged row for chunk p=0 (p=1 is +64)
  const int kc0 = (tid & 3) * 8;   // k offset within BK
  char* AsB = (char*)As;
  char* BsB = (char*)Bs;

  for (int kt = 0; kt < K; kt += 32) {
    gld_lds16(A  + (size_t)(mbase + r0)      * K + kt + kc0, AsB + wid * 1024);
    gld_lds16(A  + (size_t)(mbase + 64 + r0) * K + kt + kc0, AsB + 4096 + wid * 1024);
    gld_lds16(Bt + (size_t)(nbase + r0)      * K + kt + kc0, BsB + wid * 1024);
    gld_lds16(Bt + (size_t)(nbase + 64 + r0) * K + kt + kc0, BsB + 4096 + wid * 1024);
    __syncthreads();  // compiler drains vmcnt before barrier

    bf16x8 af[4], bfv[4];
#pragma unroll
    for (int m = 0; m < 4; ++m)
      af[m] = *reinterpret_cast<const bf16x8*>(&As[(wr * 64 + m * 16 + l15) * 32 + lhi * 8]);
#pragma unroll
    for (int n = 0; n < 4; ++n)
      bfv[n] = *reinterpret_cast<const bf16x8*>(&Bs[(wc * 64 + n * 16 + l15) * 32 + lhi * 8]);
#pragma unroll
    for (int m = 0; m < 4; ++m)
#pragma unroll
      for (int n = 0; n < 4; ++n)
        acc[m][n] = MFMA16(af[m], bfv[n], acc[m][n]);
    __syncthreads();
  }

  // epilogue: D layout col = lane&15, row = (lane>>4)*4 + j
#pragma unroll
  for (int n = 0; n < 4; ++n) {
    const int col = nbase + wc * 64 + n * 16 + l15;
    if (MODE == 0) {
      const int seg  = col >> 10;      // 0=Q 1=K 2=V (uniform per block: N tiles are 128-wide)
      const int ncol = col & 1023;
      const float* bias = (seg == 0) ? bias0 : (seg == 1) ? bias1 : bias2;
      const float bv_ = bias[ncol];
      const int h = ncol >> 6, dk = ncol & 63;
#pragma unroll
      for (int m = 0; m < 4; ++m) {
#pragma unroll
        for (int j = 0; j < 4; ++j) {
          const int row = mbase + wr * 64 + m * 16 + lhi * 4 + j;
          const int b = row >> 11, t = row & 2047;
          const int bh = b * H_ + h;
          float outv = acc[m][n][j] + bv_;
          if (seg == 0) outv *= SCALE_Q;  // fold 1/sqrt(dk)*log2(e) into Q
          const bf16 hv = __float2bfloat16(outv);
          if (seg == 0)      Qb[((size_t)bh * T_ + t) * DK_ + dk] = hv;
          else if (seg == 1) Kb[((size_t)bh * T_ + t) * DK_ + dk] = hv;
          else               Vt[((size_t)bh * DK_ + dk) * T_ + t] = hv;  // transposed V
        }
      }
    } else {
      const float bv_ = bias0[col];
#pragma unroll
      for (int m = 0; m < 4; ++m)
#pragma unroll
        for (int j = 0; j < 4; ++j) {
          const int row = mbase + wr * 64 + m * 16 + lhi * 4 + j;
          outp[(size_t)row * D_ + col] = acc[m][n][j] + bv_;
        }
    }
  }
}

// ---------------- flash attention (causal): LDS-staged K/V, double-buffered ----------------
// Block = 8 waves x 16 q-rows = 128 q rows. KV tile = 64, shared via LDS.
// Q: [BH][T][64] bf16 (pre-scaled by SCALE_Q => softmax in exp2 domain).
// K: [BH][T][64].  Vt: [BH][64][T].
// LDS K/V tiles [64 rows][8 chunks of 16B], chunk c at slot c^(r&7) (T2 swizzle via
// pre-swizzled global SOURCE, rule 21; reads apply the same XOR).
// Row-sum of P computed by MFMA with an all-ones B operand (l-accumulator shares O's
// C-layout and online rescaling) -- no sum shuffle tree.
#define PSTR 72  // P transpose buffer row stride in bf16 (144B)
__global__ __launch_bounds__(512, 4) void attn_kernel(const bf16* __restrict__ Q,
                                                      const bf16* __restrict__ Kg,
                                                      const bf16* __restrict__ Vt,
                                                      bf16* __restrict__ Mg) {
  __shared__ __align__(16) bf16 Kl[2][64 * 64];
  __shared__ __align__(16) bf16 Vl[2][64 * 64];
  __shared__ __align__(16) bf16 plds[8][16 * PSTR];
  const int tid = threadIdx.x, lane = tid & 63, wid = tid >> 6;
  const int l15 = lane & 15, lhi = lane >> 4;
  const int g  = blockIdx.x >> 5;             // 0..15
  const int qt = (g < 8) ? g : 23 - g;        // balanced pairing: qt(g)+qt(g+8)=15
  const int bh = blockIdx.x & 31;
  const int qbase = qt * 128 + wid * 16;
  const int b = bh >> 4, h = bh & 15;

  const bf16* Qp = Q  + (size_t)bh * T_ * DK_;
  const bf16* Kp = Kg + (size_t)bh * T_ * DK_;
  const bf16* Vp = Vt + (size_t)bh * DK_ * T_;

  const bf16x8 qf0 = *reinterpret_cast<const bf16x8*>(&Qp[(size_t)(qbase + l15) * DK_ + lhi * 8]);
  const bf16x8 qf1 = *reinterpret_cast<const bf16x8*>(&Qp[(size_t)(qbase + l15) * DK_ + 32 + lhi * 8]);

  bf16x8 onesb;
#pragma unroll
  for (int i = 0; i < 8; ++i) onesb[i] = (__bf16)1.0f;

  f32x4 o[4] = {};
  f32x4 lacc = {};
  float mrow[4] = {-1e30f, -1e30f, -1e30f, -1e30f};
  bf16* pw = plds[wid];

  const int nt = 2 * qt + 2;  // kv tiles (64 wide) for 128 q-rows

  // stage tile `tile` into buffer bi: 512 threads x 1 chunk each for K and V.
  // dest chunk = tid (linear); source chunk cs = (tid&7) ^ (row&7)  [T2 swizzle]
#define STAGE_KV(bi, tile)                                                       \
  {                                                                              \
    const int kvs = (tile) * 64;                                                 \
    const int r_  = tid >> 3;                                                    \
    const int cs_ = (tid & 7) ^ (r_ & 7);                                        \
    const int ub_ = wid * 1024; /* wave-uniform LDS byte base */                 \
    gld_lds16(Kp + (size_t)(kvs + r_) * DK_ + cs_ * 8, (char*)Kl[bi] + ub_);     \
    gld_lds16(Vp + (size_t)r_ * T_ + kvs + cs_ * 8,    (char*)Vl[bi] + ub_);     \
  }

  STAGE_KV(0, 0);
  __syncthreads();

  for (int t = 0; t < nt; ++t) {
    const int kv0 = t * 64;
    const int cur = t & 1;
    if (t + 1 < nt) STAGE_KV((t + 1) & 1, t + 1);  // overlap staging with compute

    if (kv0 <= qbase + 15) {  // wave-uniform: wave has live columns in this tile
      const char* Kb_ = (const char*)Kl[cur];
      const char* Vb_ = (const char*)Vl[cur];
      const int rsw = (l15 & 7);  // row-derived XOR for swizzled chunk reads

      // ---- S = Q K^T : 4 s-tiles of 16 cols; skip tiles fully above causal line
      f32x4 sv[4];
#pragma unroll
      for (int s = 0; s < 4; ++s) {
        const int cbase = kv0 + s * 16;
        if (cbase <= qbase + 15) {
          const int row = s * 16 + l15;
          const bf16x8 k0 = *reinterpret_cast<const bf16x8*>(Kb_ + row * 128 + ((lhi       ^ rsw) * 16));
          const bf16x8 k1 = *reinterpret_cast<const bf16x8*>(Kb_ + row * 128 + (((4 + lhi) ^ rsw) * 16));
          f32x4 z = {};
          z = MFMA16(qf0, k0, z);
          sv[s] = MFMA16(qf1, k1, z);
        } else {
#pragma unroll
          for (int j = 0; j < 4; ++j) sv[s][j] = -1e30f;
        }
      }

      // ---- causal mask: only the diagonal-straddling s-tile needs per-element cndmask
#pragma unroll
      for (int s = 0; s < 4; ++s) {
        const int cbase = kv0 + s * 16;
        if (cbase <= qbase + 15 && cbase + 15 > qbase) {
          const int c = cbase + l15;
#pragma unroll
          for (int j = 0; j < 4; ++j) {
            const int r = qbase + lhi * 4 + j;
            sv[s][j] = (c <= r) ? sv[s][j] : -1e30f;
          }
        }
      }

      // ---- online softmax (exp2 domain); row max via 4-level shuffle tree
      float mx[4];
#pragma unroll
      for (int j = 0; j < 4; ++j)
        mx[j] = fmaxf(fmaxf(sv[0][j], sv[1][j]), fmaxf(sv[2][j], sv[3][j]));
#pragma unroll
      for (int off = 8; off >= 1; off >>= 1)
#pragma unroll
        for (int j = 0; j < 4; ++j)
          mx[j] = fmaxf(mx[j], __shfl_xor(mx[j], off, 64));

      float sc[4];
#pragma unroll
      for (int j = 0; j < 4; ++j) {
        const float mn = fmaxf(mrow[j], mx[j]);
        sc[j] = exp2f(mrow[j] - mn);
        mrow[j] = mn;
#pragma unroll
        for (int s = 0; s < 4; ++s) sv[s][j] = exp2f(sv[s][j] - mn);
      }

#pragma unroll
      for (int j = 0; j < 4; ++j) {
        lacc[j] *= sc[j];
        o[0][j] *= sc[j]; o[1][j] *= sc[j]; o[2][j] *= sc[j]; o[3][j] *= sc[j];
      }

      // ---- transpose P via per-wave LDS: buffer[q = lhi*4+j][kv = s*16+l15]
#pragma unroll
      for (int s = 0; s < 4; ++s)
#pragma unroll
        for (int j = 0; j < 4; ++j)
          pw[(lhi * 4 + j) * PSTR + s * 16 + l15] = __float2bfloat16(sv[s][j]);
      asm volatile("s_waitcnt lgkmcnt(0)" ::: "memory");  // wave-internal write->read fence
      const bf16x8 pf0 = *reinterpret_cast<const bf16x8*>(&pw[l15 * PSTR + lhi * 8]);
      const bf16x8 pf1 = *reinterpret_cast<const bf16x8*>(&pw[l15 * PSTR + 32 + lhi * 8]);

      // ---- V fragments from LDS (after softmax: lower VGPR pressure)
      bf16x8 vf[8];
#pragma unroll
      for (int d = 0; d < 4; ++d) {
        const int row = d * 16 + l15;
#pragma unroll
        for (int s2 = 0; s2 < 2; ++s2)
          vf[d * 2 + s2] = *reinterpret_cast<const bf16x8*>(
              Vb_ + row * 128 + (((s2 * 4 + lhi) ^ rsw) * 16));
      }

      // ---- O += P V ; row-sums l += P 1 (same C layout & rescale as O)
#pragma unroll
      for (int d = 0; d < 4; ++d) {
        o[d] = MFMA16(pf0, vf[d * 2 + 0], o[d]);
        o[d] = MFMA16(pf1, vf[d * 2 + 1], o[d]);
      }
      lacc = MFMA16(pf0, onesb, lacc);
      lacc = MFMA16(pf1, onesb, lacc);
    }

    __syncthreads();  // drains vmcnt (next tile staged) + orders buffer reuse
  }

#pragma unroll
  for (int j = 0; j < 4; ++j) {
    const float inv = 1.0f / lacc[j];
    const int t = qbase + lhi * 4 + j;
#pragma unroll
    for (int d = 0; d < 4; ++d)
      Mg[((size_t)b * T_ + t) * D_ + h * DK_ + d * 16 + l15] = __float2bfloat16(o[d][j] * inv);
  }
}

// ---------------- launch ----------------
extern "C" void kernel_launch(void* const* d_in, const int* in_sizes, int n_in,
                              void* d_out, int out_size, void* d_ws, size_t ws_size,
                              hipStream_t stream) {
  (void)in_sizes; (void)n_in; (void)out_size; (void)ws_size;
  const float* x  = (const float*)d_in[0];
  const float* Wq = (const float*)d_in[1];
  const float* bq = (const float*)d_in[2];
  const float* Wk = (const float*)d_in[3];
  const float* bk = (const float*)d_in[4];
  const float* Wv = (const float*)d_in[5];
  const float* bv = (const float*)d_in[6];
  const float* Wo = (const float*)d_in[7];
  const float* bo = (const float*)d_in[8];
  float* out = (float*)d_out;

  // workspace layout (40 MB): Mg aliases xb (xb dead after QKV GEMM, attn runs after)
  char* ws = (char*)d_ws;
  bf16* xb  = (bf16*)(ws);                       // 8 MB [4096][1024]
  bf16* Mg  = (bf16*)(ws);                       // 8 MB [4096][1024] (alias, written by attn)
  bf16* Wt  = (bf16*)(ws + (size_t)( 8u << 20)); // 6 MB [3072][1024] (Wq|Wk|Wv transposed)
  bf16* Wot = (bf16*)(ws + (size_t)(14u << 20)); // 2 MB [1024][1024] (Wo transposed)
  bf16* Qb  = (bf16*)(ws + (size_t)(16u << 20)); // 8 MB [32][2048][64]
  bf16* Kb  = (bf16*)(ws + (size_t)(24u << 20)); // 8 MB [32][2048][64]
  bf16* Vt  = (bf16*)(ws + (size_t)(32u << 20)); // 8 MB [32][64][2048]

  pack_x_kernel<<<4096, 256, 0, stream>>>(x, xb);
  pack_w_kernel<<<1024, 256, 0, stream>>>(Wq, Wk, Wv, Wo, Wt, Wot);
  // fused QKV: C[4096][3072] = xb @ [Wq|Wk|Wv]
  gemm128_kernel<0><<<dim3(24, 32), 256, 0, stream>>>(xb, Wt, bq, bk, bv, Qb, Kb, Vt, nullptr, 1024);
  attn_kernel<<<dim3(512), 512, 0, stream>>>(Qb, Kb, Vt, Mg);
  // out[4096][1024] = Mg @ Wo + bo
  gemm128_kernel<1><<<dim3(8, 32), 256, 0, stream>>>(Mg, Wot, bo, nullptr, nullptr, nullptr, nullptr, nullptr, out, 1024);
}

// Round 5
// 145.646 us; speedup vs baseline: 2.1210x; 1.0686x over previous
//
#include <hip/hip_runtime.h>
#include <hip/hip_bf16.h>
#include <cstdint>
#include <cstddef>

// MHA forward: B=2, T=2048, D=1024, H=16, dk=64. fp32 in/out, bf16 MFMA internal.
#define B_  2
#define T_  2048
#define D_  1024
#define H_  16
#define DK_ 64

typedef __hip_bfloat16 bf16;
typedef __bf16 bf16x8 __attribute__((ext_vector_type(8)));  // MFMA A/B frag (4 VGPRs)
typedef float  f32x4  __attribute__((ext_vector_type(4)));  // MFMA C/D frag

#define MFMA16(a, b, c) __builtin_amdgcn_mfma_f32_16x16x32_bf16((a), (b), (c), 0, 0, 0)

// Q production scale: 1/sqrt(64) * log2(e)  (softmax done in exp2 domain)
#define SCALE_Q 0.1803368801111137f

__device__ static inline void gld_lds16(const void* g, void* l) {
  // async global->LDS, 16B per lane; LDS dest is wave-uniform base + lane*16
  __builtin_amdgcn_global_load_lds((const __attribute__((address_space(1))) void*)g,
                                   (__attribute__((address_space(3))) void*)l, 16, 0, 0);
}

// ---------------- pack: x fp32 -> bf16 ----------------
__global__ __launch_bounds__(256) void pack_x_kernel(const float* __restrict__ x,
                                                     bf16* __restrict__ xb) {
  const int i = blockIdx.x * 256 + threadIdx.x;  // exactly 1M threads, 4 elems each
  const float4 v = reinterpret_cast<const float4*>(x)[i];
  union { ushort4 u; bf16 h[4]; } c;
  c.h[0] = __float2bfloat16(v.x);
  c.h[1] = __float2bfloat16(v.y);
  c.h[2] = __float2bfloat16(v.z);
  c.h[3] = __float2bfloat16(v.w);
  reinterpret_cast<ushort4*>(xb)[i] = c.u;
}

// ---------------- pack: W (D,D) fp32 row-major [k][n] -> bf16 transposed [n][k] ----------------
__global__ __launch_bounds__(256) void pack_w_kernel(const float* __restrict__ Wq,
                                                     const float* __restrict__ Wk,
                                                     const float* __restrict__ Wv,
                                                     const float* __restrict__ Wo,
                                                     bf16* __restrict__ Wt,    // [3072][1024]
                                                     bf16* __restrict__ Wot) { // [1024][1024]
  __shared__ bf16 t[64][65];  // +1 pad breaks bank conflicts on transposed read
  const int bid  = blockIdx.x;
  const int mat  = bid >> 8;       // 0..3 : Wq,Wk,Wv,Wo
  const int tile = bid & 255;      // 16x16 tiles of 64x64
  const int tr = tile >> 4, tc = tile & 15;
  const float* W = (mat == 0) ? Wq : (mat == 1) ? Wk : (mat == 2) ? Wv : Wo;
  const int tid = threadIdx.x;
#pragma unroll
  for (int i = 0; i < 16; ++i) {
    const int idx = i * 256 + tid;
    const int r = idx >> 6, c = idx & 63;
    t[r][c] = __float2bfloat16(W[(size_t)(tr * 64 + r) * D_ + tc * 64 + c]);
  }
  __syncthreads();
  bf16* dst = (mat == 3) ? Wot : (Wt + (size_t)mat * D_ * D_);
#pragma unroll
  for (int i = 0; i < 16; ++i) {
    const int idx = i * 256 + tid;
    const int n = idx >> 6, k = idx & 63;
    dst[(size_t)(tc * 64 + n) * D_ + tr * 64 + k] = t[k][n];
  }
}

// ---------------- 128x128 bf16 GEMM, BK=32, 4 waves (2x2 of 64x64) ----------------
// A: [M][K] row-major bf16.  Bt: [N][K] row-major bf16 (i.e. B transposed).
// MODE 0: QKV epilogue -> Qb/Kb [BH][T][64], Vt [BH][64][T], + bias; Q scaled by SCALE_Q.
// MODE 1: out epilogue -> fp32 [M][1024] + bias0
template <int MODE>
__global__ __launch_bounds__(256, 2) void gemm128_kernel(
    const bf16* __restrict__ A, const bf16* __restrict__ Bt,
    const float* __restrict__ bias0, const float* __restrict__ bias1,
    const float* __restrict__ bias2,
    bf16* __restrict__ Qb, bf16* __restrict__ Kb, bf16* __restrict__ Vt,
    float* __restrict__ outp, int K) {
  __shared__ bf16 As[128 * 32];
  __shared__ bf16 Bs[128 * 32];
  const int tid  = threadIdx.x;
  const int lane = tid & 63, wid = tid >> 6;
  const int wr = wid >> 1, wc = wid & 1;
  const int l15 = lane & 15, lhi = lane >> 4;
  const int mbase = blockIdx.y * 128, nbase = blockIdx.x * 128;

  f32x4 acc[4][4] = {};

  const int r0  = tid >> 2;        // staged row for chunk p=0 (p=1 is +64)
  const int kc0 = (tid & 3) * 8;   // k offset within BK
  char* AsB = (char*)As;
  char* BsB = (char*)Bs;

  for (int kt = 0; kt < K; kt += 32) {
    gld_lds16(A  + (size_t)(mbase + r0)      * K + kt + kc0, AsB + wid * 1024);
    gld_lds16(A  + (size_t)(mbase + 64 + r0) * K + kt + kc0, AsB + 4096 + wid * 1024);
    gld_lds16(Bt + (size_t)(nbase + r0)      * K + kt + kc0, BsB + wid * 1024);
    gld_lds16(Bt + (size_t)(nbase + 64 + r0) * K + kt + kc0, BsB + 4096 + wid * 1024);
    __syncthreads();  // compiler drains vmcnt before barrier

    bf16x8 af[4], bfv[4];
#pragma unroll
    for (int m = 0; m < 4; ++m)
      af[m] = *reinterpret_cast<const bf16x8*>(&As[(wr * 64 + m * 16 + l15) * 32 + lhi * 8]);
#pragma unroll
    for (int n = 0; n < 4; ++n)
      bfv[n] = *reinterpret_cast<const bf16x8*>(&Bs[(wc * 64 + n * 16 + l15) * 32 + lhi * 8]);
#pragma unroll
    for (int m = 0; m < 4; ++m)
#pragma unroll
      for (int n = 0; n < 4; ++n)
        acc[m][n] = MFMA16(af[m], bfv[n], acc[m][n]);
    __syncthreads();
  }

  // epilogue: D layout col = lane&15, row = (lane>>4)*4 + j
#pragma unroll
  for (int n = 0; n < 4; ++n) {
    const int col = nbase + wc * 64 + n * 16 + l15;
    if (MODE == 0) {
      const int seg  = col >> 10;      // 0=Q 1=K 2=V (uniform per block: N tiles are 128-wide)
      const int ncol = col & 1023;
      const float* bias = (seg == 0) ? bias0 : (seg == 1) ? bias1 : bias2;
      const float bv_ = bias[ncol];
      const int h = ncol >> 6, dk = ncol & 63;
#pragma unroll
      for (int m = 0; m < 4; ++m) {
#pragma unroll
        for (int j = 0; j < 4; ++j) {
          const int row = mbase + wr * 64 + m * 16 + lhi * 4 + j;
          const int b = row >> 11, t = row & 2047;
          const int bh = b * H_ + h;
          float outv = acc[m][n][j] + bv_;
          if (seg == 0) outv *= SCALE_Q;  // fold 1/sqrt(dk)*log2(e) into Q
          const bf16 hv = __float2bfloat16(outv);
          if (seg == 0)      Qb[((size_t)bh * T_ + t) * DK_ + dk] = hv;
          else if (seg == 1) Kb[((size_t)bh * T_ + t) * DK_ + dk] = hv;
          else               Vt[((size_t)bh * DK_ + dk) * T_ + t] = hv;  // transposed V
        }
      }
    } else {
      const float bv_ = bias0[col];
#pragma unroll
      for (int m = 0; m < 4; ++m)
#pragma unroll
        for (int j = 0; j < 4; ++j) {
          const int row = mbase + wr * 64 + m * 16 + lhi * 4 + j;
          outp[(size_t)row * D_ + col] = acc[m][n][j] + bv_;
        }
    }
  }
}

// ---------------- flash attention (causal): LDS-staged K/V, double-buffered ----------------
// Intra-block causal pairing for load balance: waves 0-3 own q-tile p, waves 4-7 own
// q-tile 31-p. Every block = 132 live wave-iters; every SIMD = 33 (one low + one high
// wave). Robust to any block->CU mapping.
// Q: [BH][T][64] bf16 (pre-scaled by SCALE_Q => softmax in exp2 domain).
// K: [BH][T][64].  Vt: [BH][64][T].
// LDS K/V tiles [64 rows][8 chunks of 16B], chunk c at slot c^(r&7) (T2 swizzle via
// pre-swizzled global SOURCE, rule 21; reads apply the same XOR).
// Row-sum of P via ones-MFMA (l shares O's C-layout/rescale). Defer-max (T13, THR=8
// in exp2 domain): skip max-tree+rescale unless some lane exceeds mrow+8.
#define PSTR 72  // P transpose buffer row stride in bf16 (144B)
__global__ __launch_bounds__(512, 4) void attn_kernel(const bf16* __restrict__ Q,
                                                      const bf16* __restrict__ Kg,
                                                      const bf16* __restrict__ Vt,
                                                      bf16* __restrict__ Mg) {
  __shared__ __align__(16) bf16 Kl[2][64 * 64];
  __shared__ __align__(16) bf16 Vl[2][64 * 64];
  __shared__ __align__(16) bf16 plds[8][16 * PSTR];
  const int tid = threadIdx.x, lane = tid & 63, wid = tid >> 6;
  const int l15 = lane & 15, lhi = lane >> 4;
  const int p  = blockIdx.x & 15;             // complementary q-tile pair index
  const int bh = blockIdx.x >> 4;             // adjacent bids share bh -> K/V L2 locality
  const int half = wid >> 2, w4 = wid & 3;
  const int qtile = half ? (31 - p) : p;
  const int qbase = qtile * 64 + w4 * 16;
  const int b = bh >> 4, h = bh & 15;

  const bf16* Qp = Q  + (size_t)bh * T_ * DK_;
  const bf16* Kp = Kg + (size_t)bh * T_ * DK_;
  const bf16* Vp = Vt + (size_t)bh * DK_ * T_;

  const bf16x8 qf0 = *reinterpret_cast<const bf16x8*>(&Qp[(size_t)(qbase + l15) * DK_ + lhi * 8]);
  const bf16x8 qf1 = *reinterpret_cast<const bf16x8*>(&Qp[(size_t)(qbase + l15) * DK_ + 32 + lhi * 8]);

  bf16x8 onesb;
#pragma unroll
  for (int i = 0; i < 8; ++i) onesb[i] = (__bf16)1.0f;

  f32x4 o[4] = {};
  f32x4 lacc = {};
  float mrow[4] = {-1e30f, -1e30f, -1e30f, -1e30f};
  bf16* pw = plds[wid];

  const int nt = 32 - p;  // kv tiles: covers high tile's causal extent (low needs <= that)

  // stage tile `tile` into buffer bi: 512 threads x 1 chunk each for K and V.
  // dest chunk = tid (linear); source chunk cs = (tid&7) ^ (row&7)  [T2 swizzle]
#define STAGE_KV(bi, tile)                                                       \
  {                                                                              \
    const int kvs = (tile) * 64;                                                 \
    const int r_  = tid >> 3;                                                    \
    const int cs_ = (tid & 7) ^ (r_ & 7);                                        \
    const int ub_ = wid * 1024; /* wave-uniform LDS byte base */                 \
    gld_lds16(Kp + (size_t)(kvs + r_) * DK_ + cs_ * 8, (char*)Kl[bi] + ub_);     \
    gld_lds16(Vp + (size_t)r_ * T_ + kvs + cs_ * 8,    (char*)Vl[bi] + ub_);     \
  }

  STAGE_KV(0, 0);
  __syncthreads();

  for (int t = 0; t < nt; ++t) {
    const int kv0 = t * 64;
    const int cur = t & 1;
    if (t + 1 < nt) STAGE_KV((t + 1) & 1, t + 1);  // overlap staging with compute

    if (kv0 <= qbase + 15) {  // wave-uniform: wave has live columns in this tile
      const char* Kb_ = (const char*)Kl[cur];
      const char* Vb_ = (const char*)Vl[cur];
      const int rsw = (l15 & 7);  // row-derived XOR for swizzled chunk reads

      // ---- S = Q K^T : 4 s-tiles of 16 cols; skip tiles fully above causal line
      f32x4 sv[4];
#pragma unroll
      for (int s = 0; s < 4; ++s) {
        const int cbase = kv0 + s * 16;
        if (cbase <= qbase + 15) {
          const int row = s * 16 + l15;
          const bf16x8 k0 = *reinterpret_cast<const bf16x8*>(Kb_ + row * 128 + ((lhi       ^ rsw) * 16));
          const bf16x8 k1 = *reinterpret_cast<const bf16x8*>(Kb_ + row * 128 + (((4 + lhi) ^ rsw) * 16));
          f32x4 z = {};
          z = MFMA16(qf0, k0, z);
          sv[s] = MFMA16(qf1, k1, z);
        } else {
#pragma unroll
          for (int j = 0; j < 4; ++j) sv[s][j] = -1e30f;
        }
      }

      // ---- causal mask: only the diagonal-straddling s-tile needs per-element cndmask
#pragma unroll
      for (int s = 0; s < 4; ++s) {
        const int cbase = kv0 + s * 16;
        if (cbase <= qbase + 15 && cbase + 15 > qbase) {
          const int c = cbase + l15;
#pragma unroll
          for (int j = 0; j < 4; ++j) {
            const int r = qbase + lhi * 4 + j;
            sv[s][j] = (c <= r) ? sv[s][j] : -1e30f;
          }
        }
      }

      // ---- online softmax (exp2 domain), defer-max (T13):
      // only run max-tree + rescale when some lane's local max exceeds mrow + 8.
      float ml[4];
#pragma unroll
      for (int j = 0; j < 4; ++j)
        ml[j] = fmaxf(fmaxf(sv[0][j], sv[1][j]), fmaxf(sv[2][j], sv[3][j]));
      bool need = false;
#pragma unroll
      for (int j = 0; j < 4; ++j) need = need || (ml[j] > mrow[j] + 8.0f);
      if (__any(need)) {
        float mx[4] = {ml[0], ml[1], ml[2], ml[3]};
#pragma unroll
        for (int off = 8; off >= 1; off >>= 1)
#pragma unroll
          for (int j = 0; j < 4; ++j)
            mx[j] = fmaxf(mx[j], __shfl_xor(mx[j], off, 64));
#pragma unroll
        for (int j = 0; j < 4; ++j) {
          const float mn = fmaxf(mrow[j], mx[j]);
          const float sc = exp2f(mrow[j] - mn);
          mrow[j] = mn;
          lacc[j] *= sc;
          o[0][j] *= sc; o[1][j] *= sc; o[2][j] *= sc; o[3][j] *= sc;
        }
      }
#pragma unroll
      for (int j = 0; j < 4; ++j)
#pragma unroll
        for (int s = 0; s < 4; ++s) sv[s][j] = exp2f(sv[s][j] - mrow[j]);

      // ---- transpose P via per-wave LDS: buffer[q = lhi*4+j][kv = s*16+l15]
#pragma unroll
      for (int s = 0; s < 4; ++s)
#pragma unroll
        for (int j = 0; j < 4; ++j)
          pw[(lhi * 4 + j) * PSTR + s * 16 + l15] = __float2bfloat16(sv[s][j]);
      asm volatile("s_waitcnt lgkmcnt(0)" ::: "memory");  // wave-internal write->read fence
      const bf16x8 pf0 = *reinterpret_cast<const bf16x8*>(&pw[l15 * PSTR + lhi * 8]);
      const bf16x8 pf1 = *reinterpret_cast<const bf16x8*>(&pw[l15 * PSTR + 32 + lhi * 8]);

      // ---- V fragments from LDS (after softmax: lower VGPR pressure)
      bf16x8 vf[8];
#pragma unroll
      for (int d = 0; d < 4; ++d) {
        const int row = d * 16 + l15;
#pragma unroll
        for (int s2 = 0; s2 < 2; ++s2)
          vf[d * 2 + s2] = *reinterpret_cast<const bf16x8*>(
              Vb_ + row * 128 + (((s2 * 4 + lhi) ^ rsw) * 16));
      }

      // ---- O += P V ; row-sums l += P 1 (same C layout & rescale as O)
#pragma unroll
      for (int d = 0; d < 4; ++d) {
        o[d] = MFMA16(pf0, vf[d * 2 + 0], o[d]);
        o[d] = MFMA16(pf1, vf[d * 2 + 1], o[d]);
      }
      lacc = MFMA16(pf0, onesb, lacc);
      lacc = MFMA16(pf1, onesb, lacc);
    }

    __syncthreads();  // drains vmcnt (next tile staged) + orders buffer reuse
  }

#pragma unroll
  for (int j = 0; j < 4; ++j) {
    const float inv = 1.0f / lacc[j];
    const int tq = qbase + lhi * 4 + j;
#pragma unroll
    for (int d = 0; d < 4; ++d)
      Mg[((size_t)b * T_ + tq) * D_ + h * DK_ + d * 16 + l15] = __float2bfloat16(o[d][j] * inv);
  }
}

// ---------------- launch ----------------
extern "C" void kernel_launch(void* const* d_in, const int* in_sizes, int n_in,
                              void* d_out, int out_size, void* d_ws, size_t ws_size,
                              hipStream_t stream) {
  (void)in_sizes; (void)n_in; (void)out_size; (void)ws_size;
  const float* x  = (const float*)d_in[0];
  const float* Wq = (const float*)d_in[1];
  const float* bq = (const float*)d_in[2];
  const float* Wk = (const float*)d_in[3];
  const float* bk = (const float*)d_in[4];
  const float* Wv = (const float*)d_in[5];
  const float* bv = (const float*)d_in[6];
  const float* Wo = (const float*)d_in[7];
  const float* bo = (const float*)d_in[8];
  float* out = (float*)d_out;

  // workspace layout (40 MB): Mg aliases xb (xb dead after QKV GEMM, attn runs after)
  char* ws = (char*)d_ws;
  bf16* xb  = (bf16*)(ws);                       // 8 MB [4096][1024]
  bf16* Mg  = (bf16*)(ws);                       // 8 MB [4096][1024] (alias, written by attn)
  bf16* Wt  = (bf16*)(ws + (size_t)( 8u << 20)); // 6 MB [3072][1024] (Wq|Wk|Wv transposed)
  bf16* Wot = (bf16*)(ws + (size_t)(14u << 20)); // 2 MB [1024][1024] (Wo transposed)
  bf16* Qb  = (bf16*)(ws + (size_t)(16u << 20)); // 8 MB [32][2048][64]
  bf16* Kb  = (bf16*)(ws + (size_t)(24u << 20)); // 8 MB [32][2048][64]
  bf16* Vt  = (bf16*)(ws + (size_t)(32u << 20)); // 8 MB [32][64][2048]

  pack_x_kernel<<<4096, 256, 0, stream>>>(x, xb);
  pack_w_kernel<<<1024, 256, 0, stream>>>(Wq, Wk, Wv, Wo, Wt, Wot);
  // fused QKV: C[4096][3072] = xb @ [Wq|Wk|Wv]
  gemm128_kernel<0><<<dim3(24, 32), 256, 0, stream>>>(xb, Wt, bq, bk, bv, Qb, Kb, Vt, nullptr, 1024);
  attn_kernel<<<dim3(512), 512, 0, stream>>>(Qb, Kb, Vt, Mg);
  // out[4096][1024] = Mg @ Wo + bo
  gemm128_kernel<1><<<dim3(8, 32), 256, 0, stream>>>(Mg, Wot, bo, nullptr, nullptr, nullptr, nullptr, nullptr, out, 1024);
}

// Round 6
// 124.086 us; speedup vs baseline: 2.4895x; 1.1737x over previous
//
#include <hip/hip_runtime.h>
#include <hip/hip_bf16.h>
#include <cstdint>
#include <cstddef>

// MHA forward: B=2, T=2048, D=1024, H=16, dk=64. fp32 in/out, bf16 MFMA internal.
#define B_  2
#define T_  2048
#define D_  1024
#define H_  16
#define DK_ 64

typedef __hip_bfloat16 bf16;
typedef __bf16 bf16x8 __attribute__((ext_vector_type(8)));  // MFMA A/B frag (4 VGPRs)
typedef float  f32x4  __attribute__((ext_vector_type(4)));  // MFMA C/D frag

#define MFMA16(a, b, c) __builtin_amdgcn_mfma_f32_16x16x32_bf16((a), (b), (c), 0, 0, 0)

// Q production scale: 1/sqrt(64) * log2(e)  (softmax done in exp2 domain)
#define SCALE_Q 0.1803368801111137f

__device__ static inline void gld_lds16(const void* g, void* l) {
  // async global->LDS, 16B per lane; LDS dest is wave-uniform base + lane*16
  __builtin_amdgcn_global_load_lds((const __attribute__((address_space(1))) void*)g,
                                   (__attribute__((address_space(3))) void*)l, 16, 0, 0);
}

__device__ static inline ushort f2bu(float x) {
  union { bf16 h; ushort u; } c;
  c.h = __float2bfloat16(x);
  return c.u;
}

// ---------------- pack: x fp32 -> bf16 ----------------
__global__ __launch_bounds__(256) void pack_x_kernel(const float* __restrict__ x,
                                                     bf16* __restrict__ xb) {
  const int i = blockIdx.x * 256 + threadIdx.x;  // exactly 1M threads, 4 elems each
  const float4 v = reinterpret_cast<const float4*>(x)[i];
  union { ushort4 u; bf16 h[4]; } c;
  c.h[0] = __float2bfloat16(v.x);
  c.h[1] = __float2bfloat16(v.y);
  c.h[2] = __float2bfloat16(v.z);
  c.h[3] = __float2bfloat16(v.w);
  reinterpret_cast<ushort4*>(xb)[i] = c.u;
}

// ---------------- pack: W (D,D) fp32 row-major [k][n] -> bf16 transposed [n][k] ----------------
__global__ __launch_bounds__(256) void pack_w_kernel(const float* __restrict__ Wq,
                                                     const float* __restrict__ Wk,
                                                     const float* __restrict__ Wv,
                                                     const float* __restrict__ Wo,
                                                     bf16* __restrict__ Wt,    // [3072][1024]
                                                     bf16* __restrict__ Wot) { // [1024][1024]
  __shared__ bf16 t[64][65];  // +1 pad breaks bank conflicts on transposed read
  const int bid  = blockIdx.x;
  const int mat  = bid >> 8;       // 0..3 : Wq,Wk,Wv,Wo
  const int tile = bid & 255;      // 16x16 tiles of 64x64
  const int tr = tile >> 4, tc = tile & 15;
  const float* W = (mat == 0) ? Wq : (mat == 1) ? Wk : (mat == 2) ? Wv : Wo;
  const int tid = threadIdx.x;
#pragma unroll
  for (int i = 0; i < 16; ++i) {
    const int idx = i * 256 + tid;
    const int r = idx >> 6, c = idx & 63;
    t[r][c] = __float2bfloat16(W[(size_t)(tr * 64 + r) * D_ + tc * 64 + c]);
  }
  __syncthreads();
  bf16* dst = (mat == 3) ? Wot : (Wt + (size_t)mat * D_ * D_);
#pragma unroll
  for (int i = 0; i < 16; ++i) {
    const int idx = i * 256 + tid;
    const int n = idx >> 6, k = idx & 63;
    dst[(size_t)(tc * 64 + n) * D_ + tr * 64 + k] = t[k][n];
  }
}

// ---------------- QKV GEMM: 128x128 bf16, BK=32, 4 waves (2x2 of 64x64) ----------------
// A: [M][K] row-major bf16.  Bt: [N][K] row-major bf16 (i.e. B transposed).
// Epilogue -> Qb/Kb [BH][T][64], Vt [BH][64][T] (V packed 4t/store), + bias;
// Q scaled by SCALE_Q.
__global__ __launch_bounds__(256, 2) void gemm_qkv_kernel(
    const bf16* __restrict__ A, const bf16* __restrict__ Bt,
    const float* __restrict__ bias0, const float* __restrict__ bias1,
    const float* __restrict__ bias2,
    bf16* __restrict__ Qb, bf16* __restrict__ Kb, bf16* __restrict__ Vt) {
  __shared__ bf16 As[128 * 32];
  __shared__ bf16 Bs[128 * 32];
  const int tid  = threadIdx.x;
  const int lane = tid & 63, wid = tid >> 6;
  const int wr = wid >> 1, wc = wid & 1;
  const int l15 = lane & 15, lhi = lane >> 4;
  const int mbase = blockIdx.y * 128, nbase = blockIdx.x * 128;

  f32x4 acc[4][4] = {};

  const int r0  = tid >> 2;        // staged row for chunk p=0 (p=1 is +64)
  const int kc0 = (tid & 3) * 8;   // k offset within BK
  char* AsB = (char*)As;
  char* BsB = (char*)Bs;

  for (int kt = 0; kt < D_; kt += 32) {
    gld_lds16(A  + (size_t)(mbase + r0)      * D_ + kt + kc0, AsB + wid * 1024);
    gld_lds16(A  + (size_t)(mbase + 64 + r0) * D_ + kt + kc0, AsB + 4096 + wid * 1024);
    gld_lds16(Bt + (size_t)(nbase + r0)      * D_ + kt + kc0, BsB + wid * 1024);
    gld_lds16(Bt + (size_t)(nbase + 64 + r0) * D_ + kt + kc0, BsB + 4096 + wid * 1024);
    __syncthreads();  // compiler drains vmcnt before barrier

    bf16x8 af[4], bfv[4];
#pragma unroll
    for (int m = 0; m < 4; ++m)
      af[m] = *reinterpret_cast<const bf16x8*>(&As[(wr * 64 + m * 16 + l15) * 32 + lhi * 8]);
#pragma unroll
    for (int n = 0; n < 4; ++n)
      bfv[n] = *reinterpret_cast<const bf16x8*>(&Bs[(wc * 64 + n * 16 + l15) * 32 + lhi * 8]);
#pragma unroll
    for (int m = 0; m < 4; ++m)
#pragma unroll
      for (int n = 0; n < 4; ++n)
        acc[m][n] = MFMA16(af[m], bfv[n], acc[m][n]);
    __syncthreads();
  }

  // epilogue: D layout col = lane&15, row = (lane>>4)*4 + j
#pragma unroll
  for (int n = 0; n < 4; ++n) {
    const int col = nbase + wc * 64 + n * 16 + l15;
    const int seg  = col >> 10;      // 0=Q 1=K 2=V (uniform per block)
    const int ncol = col & 1023;
    const float* bias = (seg == 0) ? bias0 : (seg == 1) ? bias1 : bias2;
    const float bv_ = bias[ncol];
    const int h = ncol >> 6, dk = ncol & 63;
    if (seg == 2) {
      // V: pack 4 consecutive t (j=0..3) into one 8B store
#pragma unroll
      for (int m = 0; m < 4; ++m) {
        const int t0 = mbase + wr * 64 + m * 16 + lhi * 4;  // multiple of 4
        const int b = t0 >> 11, t = t0 & 2047;
        union { ushort u[4]; uint2 v; } pk;
#pragma unroll
        for (int j = 0; j < 4; ++j) pk.u[j] = f2bu(acc[m][n][j] + bv_);
        *reinterpret_cast<uint2*>(&Vt[((size_t)(b * H_ + h) * DK_ + dk) * T_ + t]) = pk.v;
      }
    } else {
#pragma unroll
      for (int m = 0; m < 4; ++m) {
#pragma unroll
        for (int j = 0; j < 4; ++j) {
          const int row = mbase + wr * 64 + m * 16 + lhi * 4 + j;
          const int b = row >> 11, t = row & 2047;
          const int bh = b * H_ + h;
          float outv = acc[m][n][j] + bv_;
          if (seg == 0) outv *= SCALE_Q;  // fold 1/sqrt(dk)*log2(e) into Q
          const bf16 hv = __float2bfloat16(outv);
          if (seg == 0) Qb[((size_t)bh * T_ + t) * DK_ + dk] = hv;
          else          Kb[((size_t)bh * T_ + t) * DK_ + dk] = hv;
        }
      }
    }
  }
}

// ---------------- out GEMM: 128x64 tile, BK=32, 4 waves (2x2 of 64x32) ----------------
// out[4096][1024] = A @ Wot^T + bias ; grid (16, 32) = 512 blocks -> 2 blocks/CU.
__global__ __launch_bounds__(256, 2) void gemm_out_kernel(
    const bf16* __restrict__ A, const bf16* __restrict__ Bt,
    const float* __restrict__ bias, float* __restrict__ outp) {
  __shared__ bf16 As[128 * 32];
  __shared__ bf16 Bs[64 * 32];
  const int tid  = threadIdx.x;
  const int lane = tid & 63, wid = tid >> 6;
  const int wr = wid >> 1, wc = wid & 1;
  const int l15 = lane & 15, lhi = lane >> 4;
  const int mbase = blockIdx.y * 128, nbase = blockIdx.x * 64;

  f32x4 acc[4][2] = {};

  const int r0  = tid >> 2;
  const int kc0 = (tid & 3) * 8;
  char* AsB = (char*)As;
  char* BsB = (char*)Bs;

  for (int kt = 0; kt < D_; kt += 32) {
    gld_lds16(A  + (size_t)(mbase + r0)      * D_ + kt + kc0, AsB + wid * 1024);
    gld_lds16(A  + (size_t)(mbase + 64 + r0) * D_ + kt + kc0, AsB + 4096 + wid * 1024);
    gld_lds16(Bt + (size_t)(nbase + r0)      * D_ + kt + kc0, BsB + wid * 1024);
    __syncthreads();

    bf16x8 af[4], bfv[2];
#pragma unroll
    for (int m = 0; m < 4; ++m)
      af[m] = *reinterpret_cast<const bf16x8*>(&As[(wr * 64 + m * 16 + l15) * 32 + lhi * 8]);
#pragma unroll
    for (int n = 0; n < 2; ++n)
      bfv[n] = *reinterpret_cast<const bf16x8*>(&Bs[(wc * 32 + n * 16 + l15) * 32 + lhi * 8]);
#pragma unroll
    for (int m = 0; m < 4; ++m)
#pragma unroll
      for (int n = 0; n < 2; ++n)
        acc[m][n] = MFMA16(af[m], bfv[n], acc[m][n]);
    __syncthreads();
  }

#pragma unroll
  for (int n = 0; n < 2; ++n) {
    const int col = nbase + wc * 32 + n * 16 + l15;
    const float bv_ = bias[col];
#pragma unroll
    for (int m = 0; m < 4; ++m)
#pragma unroll
      for (int j = 0; j < 4; ++j) {
        const int row = mbase + wr * 64 + m * 16 + lhi * 4 + j;
        outp[(size_t)row * D_ + col] = acc[m][n][j] + bv_;
      }
  }
}

// ---------------- flash attention (causal): LDS-staged K/V, swapped QK^T ----------------
// Intra-block causal pairing: waves 0-3 own q-tile p, waves 4-7 own q-tile 31-p
// (uniform 33 live wave-iters/SIMD regardless of block->CU mapping).
// SWAPPED S^T = mfma(K,Q): lane owns ONE q-row (q = l15); kv = kv0 + s*16 + lhi*4 + j.
// Softmax: in-lane max (15 fmax); T13 defer-max skips reduce+rescale unless some lane
// exceeds mrow+8 (then 2 shuffles + ds_bpermute broadcast of sc into O-layout).
// P transpose to LDS: 4x ds_write_b64 (kv-contiguous), read back as A-frag b128.
// Row-sum of P via ones-MFMA (lacc shares O's C-layout/rescale).
#define PSTR 72  // P transpose buffer row stride in bf16 (144B)
__global__ __launch_bounds__(512, 4) void attn_kernel(const bf16* __restrict__ Q,
                                                      const bf16* __restrict__ Kg,
                                                      const bf16* __restrict__ Vt,
                                                      bf16* __restrict__ Mg) {
  __shared__ __align__(16) bf16 Kl[2][64 * 64];
  __shared__ __align__(16) bf16 Vl[2][64 * 64];
  __shared__ __align__(16) bf16 plds[8][16 * PSTR];
  const int tid = threadIdx.x, lane = tid & 63, wid = tid >> 6;
  const int l15 = lane & 15, lhi = lane >> 4;
  const int p  = blockIdx.x & 15;             // complementary q-tile pair index
  const int bh = blockIdx.x >> 4;             // adjacent bids share bh -> K/V L2 locality
  const int half = wid >> 2, w4 = wid & 3;
  const int qtile = half ? (31 - p) : p;
  const int qbase = qtile * 64 + w4 * 16;
  const int b = bh >> 4, h = bh & 15;

  const bf16* Qp = Q  + (size_t)bh * T_ * DK_;
  const bf16* Kp = Kg + (size_t)bh * T_ * DK_;
  const bf16* Vp = Vt + (size_t)bh * DK_ * T_;

  const bf16x8 qf0 = *reinterpret_cast<const bf16x8*>(&Qp[(size_t)(qbase + l15) * DK_ + lhi * 8]);
  const bf16x8 qf1 = *reinterpret_cast<const bf16x8*>(&Qp[(size_t)(qbase + l15) * DK_ + 32 + lhi * 8]);

  bf16x8 onesb;
#pragma unroll
  for (int i = 0; i < 8; ++i) onesb[i] = (__bf16)1.0f;

  f32x4 o[4] = {};
  f32x4 lacc = {};
  float mrow = -1e30f;  // running max for this lane's q-row (q = qbase + l15)
  bf16* pw = plds[wid];

  const int nt = 32 - p;  // kv tiles: covers high tile's causal extent

  // stage tile `tile` into buffer bi: 512 threads x 1 chunk each for K and V.
  // dest chunk = tid (linear); source chunk cs = (tid&7) ^ (row&7)  [T2 swizzle]
#define STAGE_KV(bi, tile)                                                       \
  {                                                                              \
    const int kvs = (tile) * 64;                                                 \
    const int r_  = tid >> 3;                                                    \
    const int cs_ = (tid & 7) ^ (r_ & 7);                                        \
    const int ub_ = wid * 1024; /* wave-uniform LDS byte base */                 \
    gld_lds16(Kp + (size_t)(kvs + r_) * DK_ + cs_ * 8, (char*)Kl[bi] + ub_);     \
    gld_lds16(Vp + (size_t)r_ * T_ + kvs + cs_ * 8,    (char*)Vl[bi] + ub_);     \
  }

  STAGE_KV(0, 0);
  __syncthreads();

  for (int t = 0; t < nt; ++t) {
    const int kv0 = t * 64;
    const int cur = t & 1;
    if (t + 1 < nt) STAGE_KV((t + 1) & 1, t + 1);  // overlap staging with compute

    if (kv0 <= qbase + 15) {  // wave-uniform: wave has live columns in this tile
      const char* Kb_ = (const char*)Kl[cur];
      const char* Vb_ = (const char*)Vl[cur];
      const int rsw = (l15 & 7);  // row-derived XOR for swizzled chunk reads

      // ---- S^T = K Q^T : lane holds q=l15; rows kv = kv0 + s*16 + lhi*4 + j
      f32x4 sv[4];
#pragma unroll
      for (int s = 0; s < 4; ++s) {
        const int cbase = kv0 + s * 16;
        if (cbase <= qbase + 15) {
          const int row = s * 16 + l15;
          const bf16x8 k0 = *reinterpret_cast<const bf16x8*>(Kb_ + row * 128 + ((lhi       ^ rsw) * 16));
          const bf16x8 k1 = *reinterpret_cast<const bf16x8*>(Kb_ + row * 128 + (((4 + lhi) ^ rsw) * 16));
          f32x4 z = {};
          z = MFMA16(k0, qf0, z);          // swapped operand order
          sv[s] = MFMA16(k1, qf1, z);
        } else {
#pragma unroll
          for (int j = 0; j < 4; ++j) sv[s][j] = -1e30f;
        }
      }

      // ---- causal mask (kv = row, q = col): only the diagonal-straddling s-tile
#pragma unroll
      for (int s = 0; s < 4; ++s) {
        const int cbase = kv0 + s * 16;
        if (cbase <= qbase + 15 && cbase + 15 > qbase) {
          const int r = qbase + l15;
#pragma unroll
          for (int j = 0; j < 4; ++j) {
            const int c = cbase + lhi * 4 + j;
            sv[s][j] = (c <= r) ? sv[s][j] : -1e30f;
          }
        }
      }

      // ---- online softmax (exp2 domain), defer-max (T13): in-lane max only
      float ml = sv[0][0];
#pragma unroll
      for (int s = 0; s < 4; ++s)
#pragma unroll
        for (int j = 0; j < 4; ++j) ml = fmaxf(ml, sv[s][j]);

      if (__any(ml > mrow + 8.0f)) {
        float mx = ml;
        mx = fmaxf(mx, __shfl_xor(mx, 16, 64));
        mx = fmaxf(mx, __shfl_xor(mx, 32, 64));
        const float mn = fmaxf(mrow, mx);
        const float sc = exp2f(mrow - mn);
        mrow = mn;
        // broadcast sc into O-layout rows: row q' = lhi*4 + j lives in lane q'
        const int sci = __float_as_int(sc);
#pragma unroll
        for (int j = 0; j < 4; ++j) {
          const float scj = __int_as_float(
              __builtin_amdgcn_ds_bpermute((lhi * 4 + j) * 4, sci));
          lacc[j] *= scj;
          o[0][j] *= scj; o[1][j] *= scj; o[2][j] *= scj; o[3][j] *= scj;
        }
      }
#pragma unroll
      for (int s = 0; s < 4; ++s)
#pragma unroll
        for (int j = 0; j < 4; ++j) sv[s][j] = exp2f(sv[s][j] - mrow);

      // ---- P -> LDS [q][kv]: 4 kv-contiguous bf16 per write (ds_write_b64)
#pragma unroll
      for (int s = 0; s < 4; ++s) {
        union { ushort u[4]; uint2 v; } pk;
#pragma unroll
        for (int j = 0; j < 4; ++j) pk.u[j] = f2bu(sv[s][j]);
        *reinterpret_cast<uint2*>(&pw[l15 * PSTR + s * 16 + lhi * 4]) = pk.v;
      }
      asm volatile("s_waitcnt lgkmcnt(0)" ::: "memory");  // wave-internal write->read fence
      const bf16x8 pf0 = *reinterpret_cast<const bf16x8*>(&pw[l15 * PSTR + lhi * 8]);
      const bf16x8 pf1 = *reinterpret_cast<const bf16x8*>(&pw[l15 * PSTR + 32 + lhi * 8]);

      // ---- V fragments from LDS
      bf16x8 vf[8];
#pragma unroll
      for (int d = 0; d < 4; ++d) {
        const int row = d * 16 + l15;
#pragma unroll
        for (int s2 = 0; s2 < 2; ++s2)
          vf[d * 2 + s2] = *reinterpret_cast<const bf16x8*>(
              Vb_ + row * 128 + (((s2 * 4 + lhi) ^ rsw) * 16));
      }

      // ---- O += P V ; row-sums l += P 1 (same C layout & rescale as O)
#pragma unroll
      for (int d = 0; d < 4; ++d) {
        o[d] = MFMA16(pf0, vf[d * 2 + 0], o[d]);
        o[d] = MFMA16(pf1, vf[d * 2 + 1], o[d]);
      }
      lacc = MFMA16(pf0, onesb, lacc);
      lacc = MFMA16(pf1, onesb, lacc);
    }

    __syncthreads();  // drains vmcnt (next tile staged) + orders buffer reuse
  }

#pragma unroll
  for (int j = 0; j < 4; ++j) {
    const float inv = 1.0f / lacc[j];
    const int tq = qbase + lhi * 4 + j;
#pragma unroll
    for (int d = 0; d < 4; ++d)
      Mg[((size_t)b * T_ + tq) * D_ + h * DK_ + d * 16 + l15] = __float2bfloat16(o[d][j] * inv);
  }
}

// ---------------- launch ----------------
extern "C" void kernel_launch(void* const* d_in, const int* in_sizes, int n_in,
                              void* d_out, int out_size, void* d_ws, size_t ws_size,
                              hipStream_t stream) {
  (void)in_sizes; (void)n_in; (void)out_size; (void)ws_size;
  const float* x  = (const float*)d_in[0];
  const float* Wq = (const float*)d_in[1];
  const float* bq = (const float*)d_in[2];
  const float* Wk = (const float*)d_in[3];
  const float* bk = (const float*)d_in[4];
  const float* Wv = (const float*)d_in[5];
  const float* bv = (const float*)d_in[6];
  const float* Wo = (const float*)d_in[7];
  const float* bo = (const float*)d_in[8];
  float* out = (float*)d_out;

  // workspace layout (40 MB): Mg aliases xb (xb dead after QKV GEMM, attn runs after)
  char* ws = (char*)d_ws;
  bf16* xb  = (bf16*)(ws);                       // 8 MB [4096][1024]
  bf16* Mg  = (bf16*)(ws);                       // 8 MB [4096][1024] (alias, written by attn)
  bf16* Wt  = (bf16*)(ws + (size_t)( 8u << 20)); // 6 MB [3072][1024] (Wq|Wk|Wv transposed)
  bf16* Wot = (bf16*)(ws + (size_t)(14u << 20)); // 2 MB [1024][1024] (Wo transposed)
  bf16* Qb  = (bf16*)(ws + (size_t)(16u << 20)); // 8 MB [32][2048][64]
  bf16* Kb  = (bf16*)(ws + (size_t)(24u << 20)); // 8 MB [32][2048][64]
  bf16* Vt  = (bf16*)(ws + (size_t)(32u << 20)); // 8 MB [32][64][2048]

  pack_x_kernel<<<4096, 256, 0, stream>>>(x, xb);
  pack_w_kernel<<<1024, 256, 0, stream>>>(Wq, Wk, Wv, Wo, Wt, Wot);
  // fused QKV: C[4096][3072] = xb @ [Wq|Wk|Wv]
  gemm_qkv_kernel<<<dim3(24, 32), 256, 0, stream>>>(xb, Wt, bq, bk, bv, Qb, Kb, Vt);
  attn_kernel<<<dim3(512), 512, 0, stream>>>(Qb, Kb, Vt, Mg);
  // out[4096][1024] = Mg @ Wo + bo
  gemm_out_kernel<<<dim3(16, 32), 256, 0, stream>>>(Mg, Wot, bo, out);
}